// Round 1
// baseline (517.880 us; speedup 1.0000x reference)
//
#include <hip/hip_runtime.h>
#include <math.h>

// TrajDecoder on MI355X (gfx950).
// Pipeline:
//   1) convert_weights: w1,w2 -> f16 into d_ws, pre-swizzled chunk layout so that
//      linear global_load_lds staging yields bank-conflict-free ds_read_b128.
//      w3 -> plain f16 table.
//   2) fused_kernel: per (64-row tile, head): h1=relu(x@w1^T+b1), h2=relu(h1@w2^T+b2),
//      preds=h2@w3sel^T+b3, all via v_mfma_f32_16x16x32_f16 (fp32 accum).
//      A-fragments resident in registers; B streamed via LDS double buffer.
//      Outputs written directly in final packed layout (pred_time, packed18), pred_2d to ws.
//   3) loss_partial/loss_final: deterministic 2-stage reduction of all loss terms
//      (both branches of the global time_valid.sum()>0 select), incl. rot6d geodesic loss.
//
// d_ws requirement: ~5.3 MB (weights f16 4MB + w3 f16 + pred2d 1MB + partials).

#define KROWS 65536
#define DH 512

typedef _Float16 f16;
typedef _Float16 half8 __attribute__((ext_vector_type(8)));
typedef float floatx4 __attribute__((ext_vector_type(4)));

#define WS_WF16   0
#define WS_W3F16  4194304
#define WS_PRED2D 4227072
#define WS_PART   5275648

__device__ __forceinline__ void glds16(const void* g, void* l) {
  __builtin_amdgcn_global_load_lds(
      (const __attribute__((address_space(1))) void*)g,
      (__attribute__((address_space(3))) void*)l, 16, 0, 0);
}

// ---------------------------------------------------------------------------
// Weight conversion. Chunk layout: block index ((m*2+layer)*32 + nc*4 + kc),
// 16 KiB each = [64 n][128 k] f16, byte offset inside block:
//   nl*256 + ((klocal*2) ^ ((nl&7)<<4))
// ---------------------------------------------------------------------------
__global__ __launch_bounds__(256) void convert_weights(
    const float* __restrict__ w1, const float* __restrict__ w2,
    const float* __restrict__ w3, f16* __restrict__ wf16, f16* __restrict__ w3f16)
{
  int idx = blockIdx.x * 256 + threadIdx.x;
  const int NW = 2 * 4 * DH * DH;  // 2097152
  if (idx < NW) {
    int which = idx >> 20;              // 0 = w1, 1 = w2
    int r = idx & ((1 << 20) - 1);
    int mm = r >> 18;                   // head
    int nk = r & ((1 << 18) - 1);
    int n = nk >> 9, k = nk & 511;
    float v = which ? w2[r] : w1[r];
    int nc = n >> 6, nl = n & 63, kc = k >> 7;
    int klb = (k & 127) * 2;
    size_t off = ((size_t)((mm * 2 + which) * 32 + nc * 4 + kc)) * 16384
               + (size_t)(nl * 256 + (klb ^ ((nl & 7) << 4)));
    *(f16*)((unsigned char*)wf16 + off) = (f16)v;
  } else {
    int j = idx - NW;
    if (j < 23 * DH) w3f16[j] = (f16)w3[j];
  }
}

// ---------------------------------------------------------------------------
// Fused 2-layer MLP + head projection.
// grid = (1024 row-tiles, 4 heads), block = 256 (4 waves, 16 rows/wave).
// ---------------------------------------------------------------------------
__global__ __launch_bounds__(256) void fused_kernel(
    const float* __restrict__ hidden,
    const f16* __restrict__ wf16,
    const f16* __restrict__ w3f16,
    const float* __restrict__ b1g,
    const float* __restrict__ b2g,
    const float* __restrict__ b3g,
    float* __restrict__ dout,
    float* __restrict__ pred2d)
{
  const int m    = blockIdx.y;
  const int tid  = threadIdx.x;
  const int wave = tid >> 6;
  const int lane = tid & 63;
  const int l15  = lane & 15;
  const int lg   = lane >> 4;
  const int r0   = blockIdx.x * 64 + wave * 16;

  __shared__ __align__(16) unsigned char ldsB[2][16384];
  __shared__ __align__(16) unsigned char ldsT[4][2048];
  unsigned char* tb = ldsT[wave];

  half8 A1[16], A2[16];
  floatx4 acc[4];
  floatx4 acc3 = {0.f, 0.f, 0.f, 0.f};
  const floatx4 zf = {0.f, 0.f, 0.f, 0.f};
  const half8 hz = {(f16)0, (f16)0, (f16)0, (f16)0, (f16)0, (f16)0, (f16)0, (f16)0};

  // ---- A1 fragments: hidden rows r0..r0+15, fp32 -> f16, k = 32q + 8*lg + i ----
  {
    const float* rp = hidden + (size_t)(r0 + l15) * DH + lg * 8;
#pragma unroll
    for (int q = 0; q < 16; ++q) {
      floatx4 u0 = *(const floatx4*)(rp + q * 32);
      floatx4 u1 = *(const floatx4*)(rp + q * 32 + 4);
      half8 a;
      a[0] = (f16)u0[0]; a[1] = (f16)u0[1]; a[2] = (f16)u0[2]; a[3] = (f16)u0[3];
      a[4] = (f16)u1[0]; a[5] = (f16)u1[1]; a[6] = (f16)u1[2]; a[7] = (f16)u1[3];
      A1[q] = a;
    }
  }

  auto stage = [&](int buf, int layer, int nc, int kc) {
    const unsigned char* src = (const unsigned char*)wf16
        + ((size_t)((m * 2 + layer) * 32 + nc * 4 + kc)) * 16384
        + (size_t)(wave * 4096 + lane * 16);
    unsigned char* dst = &ldsB[buf][wave * 4096];
#pragma unroll
    for (int i = 0; i < 4; ++i) glds16(src + i * 1024, dst + i * 1024);
  };

  auto bfrag = [&](int buf, int s, int kk) -> half8 {
    int nl = 16 * s + l15;
    int kb = 64 * kk + 16 * lg;
    return *(const half8*)(&ldsB[buf][nl * 256 + (kb ^ ((nl & 7) << 4))]);
  };

  // transpose-buffer read: A-fragment of the freshly produced activation tile.
  auto tread = [&](int kk) -> half8 {
    int col0 = 32 * kk + 8 * lg;
    int s = col0 >> 4, c0 = col0 & 15;
    int j = l15 & 3, g2 = l15 >> 2;
    return *(const half8*)(&tb[(s * 4 + j) * 128 + (((g2 * 16 + c0) * 2) ^ (j << 4))]);
  };

  stage(0, 0, 0, 0);
  __syncthreads();

  // ================= layer 1: h1 = relu(x @ w1^T + b1) =================
#pragma unroll
  for (int nc = 0; nc < 8; ++nc) {
    acc[0] = zf; acc[1] = zf; acc[2] = zf; acc[3] = zf;
#pragma unroll
    for (int kc = 0; kc < 4; ++kc) {
      const int g = nc * 4 + kc;
      { const int ng = g + 1;  // <= 32, crosses into layer-2 chunk 0 at ng==32
        stage(ng & 1, ng >> 5, (ng & 31) >> 2, ng & 3); }
      const int buf = g & 1;
#pragma unroll
      for (int kk = 0; kk < 4; ++kk) {
#pragma unroll
        for (int s = 0; s < 4; ++s)
          acc[s] = __builtin_amdgcn_mfma_f32_16x16x32_f16(
              A1[kc * 4 + kk], bfrag(buf, s, kk), acc[s], 0, 0, 0);
      }
      if (kc == 3) {
        // bias + relu -> f16 -> per-wave transpose buffer (conflict-free writes)
#pragma unroll
        for (int s = 0; s < 4; ++s) {
          const float bv = b1g[m * DH + 64 * nc + 16 * s + l15];
#pragma unroll
          for (int j = 0; j < 4; ++j) {
            float h = fmaxf(acc[s][j] + bv, 0.f);
            *(f16*)(&tb[(s * 4 + j) * 128 + ((lane * 2) ^ (j << 4))]) = (f16)h;
          }
        }
        A2[nc * 2 + 0] = tread(0);
        A2[nc * 2 + 1] = tread(1);
      }
      __syncthreads();
    }
  }

  // ================= layer 2 + fused head =================
  const int base_m = (m == 0) ? 0 : (m == 1) ? 1 : (m == 2) ? 7 : 11;
  const int cnt_m  = (m == 0) ? 1 : (m == 1) ? 6 : (m == 2) ? 4 : 12;
  const bool ovalid = l15 < cnt_m;
  const f16* w3row = w3f16 + (size_t)(base_m + (ovalid ? l15 : 0)) * DH;

#pragma unroll
  for (int nc = 0; nc < 8; ++nc) {
    acc[0] = zf; acc[1] = zf; acc[2] = zf; acc[3] = zf;
#pragma unroll
    for (int kc = 0; kc < 4; ++kc) {
      const int g = 32 + nc * 4 + kc;
      if (g + 1 < 64) { const int ng = g + 1;
        stage(ng & 1, 1, (ng & 31) >> 2, ng & 3); }
      const int buf = g & 1;
#pragma unroll
      for (int kk = 0; kk < 4; ++kk) {
#pragma unroll
        for (int s = 0; s < 4; ++s)
          acc[s] = __builtin_amdgcn_mfma_f32_16x16x32_f16(
              A2[kc * 4 + kk], bfrag(buf, s, kk), acc[s], 0, 0, 0);
      }
      if (kc == 3) {
#pragma unroll
        for (int s = 0; s < 4; ++s) {
          const float bv = b2g[m * DH + 64 * nc + 16 * s + l15];
#pragma unroll
          for (int j = 0; j < 4; ++j) {
            float h = fmaxf(acc[s][j] + bv, 0.f);
            *(f16*)(&tb[(s * 4 + j) * 128 + ((lane * 2) ^ (j << 4))]) = (f16)h;
          }
        }
        const half8 a3a = tread(0);
        const half8 a3b = tread(1);
        const half8 b3a = ovalid ? *(const half8*)(w3row + 64 * nc + 8 * lg) : hz;
        const half8 b3b = ovalid ? *(const half8*)(w3row + 64 * nc + 32 + 8 * lg) : hz;
        acc3 = __builtin_amdgcn_mfma_f32_16x16x32_f16(a3a, b3a, acc3, 0, 0, 0);
        acc3 = __builtin_amdgcn_mfma_f32_16x16x32_f16(a3b, b3b, acc3, 0, 0, 0);
      }
      __syncthreads();
    }
  }

  // ---- epilogue: write predictions (packed layout) ----
  if (ovalid) {
    const float bo = b3g[base_m + l15];
#pragma unroll
    for (int j = 0; j < 4; ++j) {
      const int row = r0 + 4 * lg + j;
      const float v = acc3[j] + bo;
      if (m == 0)      { if (l15 == 0) dout[row] = v; }
      else if (m == 1) { dout[KROWS + row * 18 + (l15 < 3 ? l15 : l15 + 6)] = v; }
      else if (m == 2) { pred2d[row * 4 + l15] = v; }
      else             { dout[KROWS + row * 18 + (l15 < 6 ? l15 + 3 : l15 + 6)] = v; }
    }
  }
}

// ---------------------------------------------------------------------------
// Loss math helpers (scalar fp32, matches jnp reference)
// ---------------------------------------------------------------------------
__device__ __forceinline__ void safe_norm3(float x, float y, float z, float* o) {
  float n = sqrtf(x * x + y * y + z * z);
  if (n > 1e-6f) { o[0] = x / n; o[1] = y / n; o[2] = z / n; }
  else           { o[0] = 1.f;   o[1] = 0.f;   o[2] = 0.f; }
}

__device__ __forceinline__ void rot6d(const float* x, float* R) {
  float a1[3]; safe_norm3(x[0], x[1], x[2], a1);
  float d = a1[0] * x[3] + a1[1] * x[4] + a1[2] * x[5];
  float b2[3]; safe_norm3(x[3] - d * a1[0], x[4] - d * a1[1], x[5] - d * a1[2], b2);
  float a3[3];
  safe_norm3(a1[1] * b2[2] - a1[2] * b2[1],
             a1[2] * b2[0] - a1[0] * b2[2],
             a1[0] * b2[1] - a1[1] * b2[0], a3);
  float bb[3];
  safe_norm3(a3[1] * a1[2] - a3[2] * a1[1],
             a3[2] * a1[0] - a3[0] * a1[2],
             a3[0] * a1[1] - a3[1] * a1[0], bb);
  R[0] = a1[0]; R[1] = a1[1]; R[2] = a1[2];
  R[3] = bb[0]; R[4] = bb[1]; R[5] = bb[2];
  R[6] = a3[0]; R[7] = a3[1]; R[8] = a3[2];
}

__device__ __forceinline__ float geo_angle(const float* P, const float* G) {
  float M[9];
#pragma unroll
  for (int i = 0; i < 3; ++i)
#pragma unroll
    for (int l = 0; l < 3; ++l)
      M[i * 3 + l] = G[0 + i] * P[0 + l] + G[3 + i] * P[3 + l] + G[6 + i] * P[6 + l];
  float tr = M[0] + M[4] + M[8];
  float c = fminf(fmaxf((tr - 1.f) * 0.5f, -1.f + 1e-6f), 1.f - 1e-6f);
  float v0 = M[7] - M[5], v1 = M[2] - M[6], v2 = M[3] - M[1];
  float s = 0.5f * sqrtf(v0 * v0 + v1 * v1 + v2 * v2) + 1e-8f;
  return atan2f(s, c);
}

// accumulators: 0 t_num 1 t_den 2 tv_sum 3..6 n3T d3T n3F d3F
//               7..10 n2T d2T n2F d2F  11..14 nqT dqT nqF dqF  15 rot_num 16 rot_den
__global__ __launch_bounds__(256) void loss_partial(
    const float* __restrict__ gt, const float* __restrict__ dout,
    const float* __restrict__ pred2d, float* __restrict__ partials)
{
  const int r = blockIdx.x * 256 + threadIdx.x;
  const float* g  = gt + (size_t)r * 23;
  const float* pk = dout + KROWS + (size_t)r * 18;
  float a[17];

  const float pt = dout[r];
  const float tg = g[0];
  const float tv = (tg != -1000.f) ? 1.f : 0.f;
  const float dt = fabsf(pt - tg);
  a[0] = ((dt < 3.f) ? (0.5f * dt * dt / 3.f) : (dt - 1.5f)) * tv;
  a[1] = tv;
  a[2] = tv;
  const float wt = expf(-0.5f * (dt / 3.f) * (dt / 3.f)) * tv;  // time-valid branch weight

  float n3T = 0.f, d3T = 0.f, n3F = 0.f, d3F = 0.f;
#pragma unroll
  for (int j = 0; j < 6; ++j) {
    const float p = pk[j < 3 ? j : j + 6];
    const float q = g[1 + j];
    const float val = (q != -1000.f) ? 1.f : 0.f;
    const float d = fabsf(p - q);
    const float l = (d < 0.07f) ? (0.5f * d * d / 0.07f) : (d - 0.035f);
    n3T += l * val * wt; d3T += val * wt; n3F += l * val; d3F += val;
  }
  a[3] = n3T; a[4] = d3T; a[5] = n3F; a[6] = d3F;

  float n2T = 0.f, d2T = 0.f, n2F = 0.f, d2F = 0.f;
#pragma unroll
  for (int j = 0; j < 4; ++j) {
    const float p = pred2d[(size_t)r * 4 + j];
    const float q = g[7 + j];
    const float val = (q != -1000.f) ? 1.f : 0.f;
    const float d = fabsf(p / 1408.f - q / 1408.f);
    const float l = (d < 0.02f) ? (0.5f * d * d / 0.02f) : (d - 0.01f);
    n2T += l * val * wt; d2T += val * wt; n2F += l * val; d2F += val;
  }
  a[7] = n2T; a[8] = d2T; a[9] = n2F; a[10] = d2F;

  float qp[12];
#pragma unroll
  for (int j = 0; j < 12; ++j) qp[j] = pk[j < 6 ? j + 3 : j + 6];
  float nqT = 0.f, dqT = 0.f, nqF = 0.f, dqF = 0.f;
#pragma unroll
  for (int j = 0; j < 12; ++j) {
    const float q = g[11 + j];
    const float val = (q != -1000.f) ? 1.f : 0.f;
    const float d = fabsf(qp[j] - q);
    const float l = (d < 0.2f) ? (0.5f * d * d / 0.2f) : (d - 0.1f);
    nqT += l * val * wt; dqT += val * wt; nqF += l * val; dqF += val;
  }
  a[11] = nqT; a[12] = dqT; a[13] = nqF; a[14] = dqF;

  bool Lv = true, Rv = true;
#pragma unroll
  for (int j = 0; j < 6; ++j) {
    if (g[11 + j] == -1000.f) Lv = false;
    if (g[17 + j] == -1000.f) Rv = false;
  }
  const float safe6[6] = {1.f, 0.f, 0.f, 0.f, 1.f, 0.f};
  float Lt[6], Rt[6];
#pragma unroll
  for (int j = 0; j < 6; ++j) {
    Lt[j] = Lv ? g[11 + j] : safe6[j];
    Rt[j] = Rv ? g[17 + j] : safe6[j];
  }
  float Rp[9], Rg[9];
  rot6d(qp, Rp);     rot6d(Lt, Rg);
  const float angL = geo_angle(Rp, Rg);
  rot6d(qp + 6, Rp); rot6d(Rt, Rg);
  const float angR = geo_angle(Rp, Rg);
  a[15] = (Lv ? angL : 0.f) + (Rv ? angR : 0.f);
  a[16] = (Lv ? 1.f : 0.f) + (Rv ? 1.f : 0.f);

  // block reduction (deterministic)
#pragma unroll
  for (int i = 0; i < 17; ++i) {
    float v = a[i];
#pragma unroll
    for (int off = 32; off > 0; off >>= 1) v += __shfl_down(v, off, 64);
    a[i] = v;
  }
  __shared__ float red[4][17];
  if ((threadIdx.x & 63) == 0) {
    const int w = threadIdx.x >> 6;
#pragma unroll
    for (int i = 0; i < 17; ++i) red[w][i] = a[i];
  }
  __syncthreads();
  if (threadIdx.x < 17)
    partials[blockIdx.x * 20 + threadIdx.x] =
        red[0][threadIdx.x] + red[1][threadIdx.x] + red[2][threadIdx.x] + red[3][threadIdx.x];
}

__global__ void loss_final(const float* __restrict__ partials, float* __restrict__ dout)
{
  __shared__ float s[17];
  const int i = threadIdx.x;
  if (i < 17) {
    float v = 0.f;
    for (int b = 0; b < 256; ++b) v += partials[b * 20 + i];
    s[i] = v;
  }
  __syncthreads();
  if (i == 0) {
    const bool flag = s[2] > 0.f;
    const float time_loss = s[0] / fmaxf(s[1], 1.f);
    const float l3 = flag ? s[3] / fmaxf(s[4], 1.f) : s[5] / fmaxf(s[6], 1.f);
    const float l2 = flag ? s[7] / fmaxf(s[8], 1.f) : s[9] / fmaxf(s[10], 1.f);
    const float lq = flag ? s[11] / fmaxf(s[12], 1.f) : s[13] / fmaxf(s[14], 1.f);
    const float rot = 0.15f * (s[15] / fmaxf(s[16], 1e-8f));
    dout[19 * KROWS] = time_loss + 2.f * l3 + 0.5f * l2 + 0.5f * lq + rot;
  }
}

// ---------------------------------------------------------------------------
extern "C" void kernel_launch(void* const* d_in, const int* in_sizes, int n_in,
                              void* d_out, int out_size, void* d_ws, size_t ws_size,
                              hipStream_t stream) {
  (void)in_sizes; (void)n_in; (void)out_size; (void)ws_size;
  const float* hidden = (const float*)d_in[0];
  const float* gt     = (const float*)d_in[1];
  const float* w1     = (const float*)d_in[2];
  const float* b1     = (const float*)d_in[3];
  const float* w2     = (const float*)d_in[4];
  const float* b2     = (const float*)d_in[5];
  const float* w3     = (const float*)d_in[6];
  const float* b3     = (const float*)d_in[7];
  float* dout = (float*)d_out;

  unsigned char* ws = (unsigned char*)d_ws;
  f16*   wf16     = (f16*)(ws + WS_WF16);
  f16*   w3f16    = (f16*)(ws + WS_W3F16);
  float* pred2d   = (float*)(ws + WS_PRED2D);
  float* partials = (float*)(ws + WS_PART);

  convert_weights<<<8238, 256, 0, stream>>>(w1, w2, w3, wf16, w3f16);
  fused_kernel<<<dim3(1024, 4), 256, 0, stream>>>(hidden, wf16, w3f16, b1, b2, b3, dout, pred2d);
  loss_partial<<<256, 256, 0, stream>>>(gt, dout, pred2d, partials);
  loss_final<<<1, 64, 0, stream>>>(partials, dout);
}